// Round 10
// baseline (185.778 us; speedup 1.0000x reference)
//
#include <hip/hip_runtime.h>
#include <hip/hip_cooperative_groups.h>
#include <stdint.h>

namespace cg = cooperative_groups;

#define NV 100000
#define EPS 1e-5f

typedef __attribute__((ext_vector_type(8))) short short8;
typedef __attribute__((ext_vector_type(4))) float f32x4;
typedef __attribute__((ext_vector_type(4))) unsigned int uint4v;

__device__ inline float bf2f(unsigned short u) {
    union { unsigned int i; float f; } v; v.i = (unsigned int)u << 16; return v.f;
}
__device__ inline unsigned short f2bf(float f) {
    union { float f; unsigned int i; } v; v.f = f;
    return (unsigned short)((v.i + 0x7fff + ((v.i >> 16) & 1)) >> 16);
}

// direct global->LDS DMA, 16B/lane; dest = wave-uniform base + lane*16
typedef __attribute__((address_space(1))) const unsigned int g_u32;
typedef __attribute__((address_space(3))) unsigned int l_u32;
__device__ __forceinline__ void gload_lds16(const void* g, void* l) {
    __builtin_amdgcn_global_load_lds((g_u32*)g, (l_u32*)l, 16, 0, 0);
}

// ---------------- ws layout (bytes) ----------------
// W1s: staged bf16 [14][4][448][8] = 401,408
// W2s: staged bf16 [13][4][448][8] = 372,736
// st : 4 replicas x [gsum1|gsq1|gsum2|gsq2][416] f32 = 26,624
#define W1S_OFF 0
#define W2S_OFF 401408
#define ST_OFF  774144

// =====================================================================
// Single cooperative kernel. grid = 256 x 512 (8 waves), 1 block/CU
// (same launch geometry as the R4 kernel that launched successfully).
// Block owns rows m0r..m0r+63. Wave wv = (rg<<2)|w4:
//   rg = row half (32 rows), w4 = col quarter (cols cb..cb+16*NFW).
// LDS regions (157,952 B total):
//  R1 [0,51200): per-wave W slices (K1,K2); later alpha2/beta2
//  R2 [51200,104448): a_s (gather->K1); al1/bt1 (K2); z2 (K2epi->final)
//  R3 [104448,157696): gather scratch+dense (->K1); z1 (K1epi->K2)
//  base_s [157696,157952)
// =====================================================================
__global__ __launch_bounds__(512, 2) void deepfm_one(
    const int* __restrict__ Xcat, const float* __restrict__ Xd,
    const float* __restrict__ fm1, const float* __restrict__ emb,
    const float* __restrict__ Wd, const float* __restrict__ bd,
    const float* __restrict__ W1, const float* __restrict__ b1,
    const float* __restrict__ g1, const float* __restrict__ be1,
    const float* __restrict__ W2, const float* __restrict__ b2,
    const float* __restrict__ g2, const float* __restrict__ be2,
    const float* __restrict__ W3, const float* __restrict__ b3,
    unsigned short* __restrict__ W1s, unsigned short* __restrict__ W2s,
    float* __restrict__ st, float* __restrict__ out)
{
    cg::grid_group grid = cg::this_grid();
    __shared__ __align__(16) char smem[157952];
    char* R2 = smem + 51200;
    char* R3 = smem + 104448;
    float* base_s = (float*)(smem + 157696);

    const int tid = threadIdx.x, bid = blockIdx.x;
    const int lane = tid & 63, wv = tid >> 6;
    const int rg = wv >> 2, w4 = wv & 3;
    const int l15 = lane & 15, qh = lane >> 4;
    const int m0r = bid * 64;
    const int cb = (w4 == 0) ? 0 : (112 + (w4 - 1) * 96);   // 0,112,208,304
    const int NFW = (w4 == 0) ? 7 : 6;
    unsigned short* slice = (unsigned short*)
        (smem + rg * 25600 + ((w4 == 0) ? 0 : (7168 + (w4 - 1) * 6144)));

    float* s_lds = (float*)R3;                        // [64][16] f32
    float* ssq   = (float*)(R3 + 4096);               // [64]
    float* fmb   = (float*)(R3 + 4352);               // [64]
    float* dsw   = (float*)(R3 + 4608);               // [64]
    unsigned short* dense_s = (unsigned short*)(R3 + 4864); // [64][16] bf16
    unsigned short* a_s = (unsigned short*)R2;        // [13][4][64][8] bf16

    // ================= stage 0: zero scratch+stats, stage W ==============
    for (int i = tid; i < 1728; i += 512) ((float*)R3)[i] = 0.f;
    if (bid < 13) st[bid * 512 + tid] = 0.f;
    {
        int c = tid * 256 + bid;            // unique over (tid,bid)
        if (c < 48384) {
            const float* W; unsigned short* dst; int K; int cc;
            if (c < 25088) { W = W1; dst = W1s; K = 429; cc = c; }
            else           { W = W2; dst = W2s; K = 400; cc = c - 25088; }
            int n = cc % 448, q = (cc / 448) & 3, kt = cc / 1792;
            unsigned short o[8];
            #pragma unroll
            for (int j = 0; j < 8; ++j) {
                int k = kt * 32 + q * 8 + j;
                float vv = (n < 400 && k < K) ? W[(size_t)k * 400 + n] : 0.f;
                o[j] = f2bf(vv);
            }
            *(uint4v*)(dst + (size_t)cc * 8) = *(uint4v*)o;
        }
    }
    __syncthreads();

    // ================= gather: 1664 (r,f) pairs + dense ==================
    {
        float v[4][16]; float fmv[4]; int pf[4], pr[4];
        #pragma unroll
        for (int i = 0; i < 4; ++i) {
            int p = tid + i * 512;
            if (p < 1664) {
                int f = p >> 6, r = p & 63;
                pf[i] = f; pr[i] = r;
                int idx = Xcat[(size_t)(m0r + r) * 26 + f];
                const float* ep = emb + ((size_t)f * NV + (size_t)idx) * 16;
                f32x4 x0 = *(const f32x4*)ep;
                f32x4 x1 = *(const f32x4*)(ep + 4);
                f32x4 x2 = *(const f32x4*)(ep + 8);
                f32x4 x3 = *(const f32x4*)(ep + 12);
                #pragma unroll
                for (int j = 0; j < 4; ++j) {
                    v[i][j] = x0[j]; v[i][4 + j] = x1[j];
                    v[i][8 + j] = x2[j]; v[i][12 + j] = x3[j];
                }
                fmv[i] = fm1[(size_t)f * NV + idx];
            }
        }
        float dvx[2]; int drr[2], dds[2];
        #pragma unroll
        for (int i = 0; i < 2; ++i) {
            int p = tid + i * 512;
            if (p < 832) {
                int r = p / 13, d = p - r * 13;
                drr[i] = r; dds[i] = d;
                dvx[i] = Xd[(size_t)(m0r + r) * 13 + d];
            }
        }
        #pragma unroll
        for (int i = 0; i < 4; ++i) {
            int p = tid + i * 512;
            if (p < 1664) {
                int f = pf[i], r = pr[i];
                int kt = f >> 1, q0 = (f & 1) * 2;
                unsigned short o[16]; float sq = 0.f;
                #pragma unroll
                for (int k = 0; k < 16; ++k) {
                    float x = v[i][k];
                    o[k] = f2bf(x); sq += x * x;
                    atomicAdd(&s_lds[r * 16 + k], x);
                }
                *(uint4v*)&a_s[(size_t)((kt * 4 + q0) * 64 + r) * 8] = *(uint4v*)&o[0];
                *(uint4v*)&a_s[(size_t)((kt * 4 + q0 + 1) * 64 + r) * 8] = *(uint4v*)&o[8];
                atomicAdd(&ssq[r], sq);
                atomicAdd(&fmb[r], fmv[i]);
            }
        }
        #pragma unroll
        for (int i = 0; i < 2; ++i) {
            int p = tid + i * 512;
            if (p < 832) {
                dense_s[drr[i] * 16 + dds[i]] = f2bf(dvx[i]);
                atomicAdd(&dsw[drr[i]], dvx[i] * Wd[dds[i]]);
            }
        }
    }
    __syncthreads();
    if (tid < 64) {     // FM finalize
        int r = tid; float a2 = 0.f;
        #pragma unroll
        for (int k = 0; k < 16; ++k) { float s = s_lds[r * 16 + k]; a2 += s * s; }
        base_s[r] = 0.5f * (a2 - ssq[r]) + fmb[r] + dsw[r] + bd[0];
    }
    grid.sync();    // S1: W1s/W2s + st zeros visible grid-wide

    // ================= K1: Z1 = X @ W1 + b1 ==============================
    float* stc = st + (bid & 3) * 1664;
    f32x4 acc0[7], acc1[7];
    #pragma unroll
    for (int i = 0; i < 7; ++i) { acc0[i] = f32x4{0,0,0,0}; acc1[i] = f32x4{0,0,0,0}; }

    #pragma unroll
    for (int i = 0; i < 7; ++i) if (i < NFW) {
        int ci = qh * 448 + cb + i * 16 + l15;
        gload_lds16(W1s + (size_t)ci * 8, slice + i * 512);
    }
    for (int kt = 0; kt < 14; ++kt) {
        asm volatile("s_waitcnt vmcnt(0)" ::: "memory");
        __builtin_amdgcn_sched_barrier(0);
        short8 bf[7];
        #pragma unroll
        for (int i = 0; i < 7; ++i) if (i < NFW)
            bf[i] = *(const short8*)(slice + i * 512 + lane * 8);
        short8 afA, afB;
        if (kt < 13) {
            afA = *(const short8*)&a_s[(size_t)((kt * 4 + qh) * 64 + rg * 32 + l15) * 8];
            afB = *(const short8*)&a_s[(size_t)((kt * 4 + qh) * 64 + rg * 32 + 16 + l15) * 8];
        } else if (qh < 2) {
            afA = *(const short8*)&dense_s[(rg * 32 + l15) * 16 + qh * 8];
            afB = *(const short8*)&dense_s[(rg * 32 + 16 + l15) * 16 + qh * 8];
        } else {
            #pragma unroll
            for (int j = 0; j < 8; ++j) { afA[j] = 0; afB[j] = 0; }
        }
        asm volatile("s_waitcnt lgkmcnt(0)" ::: "memory");
        __builtin_amdgcn_sched_barrier(0);
        if (kt < 13) {
            #pragma unroll
            for (int i = 0; i < 7; ++i) if (i < NFW) {
                int ci = ((kt + 1) * 4 + qh) * 448 + cb + i * 16 + l15;
                gload_lds16(W1s + (size_t)ci * 8, slice + i * 512);
            }
        }
        #pragma unroll
        for (int i = 0; i < 7; ++i) if (i < NFW) {
            acc0[i] = __builtin_amdgcn_mfma_f32_16x16x32_bf16(afA, bf[i], acc0[i], 0, 0, 0);
            acc1[i] = __builtin_amdgcn_mfma_f32_16x16x32_bf16(afB, bf[i], acc1[i], 0, 0, 0);
        }
    }
    __syncthreads();    // all waves done with a_s/dense_s before z1 overwrites R3
    unsigned short* z1 = (unsigned short*)R3;    // [64][416]
    #pragma unroll
    for (int i = 0; i < 7; ++i) if (i < NFW) {
        int col = cb + i * 16 + l15;
        float bv = b1[col];
        float ps = 0.f, pq = 0.f;
        #pragma unroll
        for (int q = 0; q < 4; ++q) {
            float v0 = acc0[i][q] + bv;
            float v1 = acc1[i][q] + bv;
            z1[(size_t)(rg * 32 + qh * 4 + q) * 416 + col] = f2bf(v0);
            z1[(size_t)(rg * 32 + 16 + qh * 4 + q) * 416 + col] = f2bf(v1);
            ps += v0 + v1; pq += v0 * v0 + v1 * v1;
        }
        ps += __shfl_xor(ps, 16, 64); ps += __shfl_xor(ps, 32, 64);
        pq += __shfl_xor(pq, 16, 64); pq += __shfl_xor(pq, 32, 64);
        if (qh == 0) { atomicAdd(&stc[col], ps); atomicAdd(&stc[416 + col], pq); }
    }
    if (w4 == 3) {       // zero pad z1 cols 400..415 (both row halves via rg)
        #pragma unroll
        for (int rr = 0; rr < 8; ++rr)
            z1[(size_t)(rg * 32 + rr * 4 + qh) * 416 + 400 + l15] = 0;
    }
    grid.sync();    // S2: stats1 complete, z1 per-block in LDS

    // ---- BN1 finalize into R2 front (a_s dead) ----
    float* al1 = (float*)R2;
    float* bt1 = (float*)(R2 + 1664);
    for (int c = tid; c < 416; c += 512) {
        float a = 0.f, b = 0.f;
        if (c < 400) {
            float gs = 0.f, gq = 0.f;
            #pragma unroll
            for (int cp = 0; cp < 4; ++cp) {
                gs += st[cp * 1664 + c];
                gq += st[cp * 1664 + 416 + c];
            }
            float mean = gs * (1.f / 16384.f);
            float var  = gq * (1.f / 16384.f) - mean * mean;
            a = g1[c] * rsqrtf(var + EPS);
            b = be1[c] - mean * a;
        }
        al1[c] = a; bt1[c] = b;
    }
    __syncthreads();

    // ================= K2: Z2 = relu(bn1(Z1)) @ W2 + b2 ==================
    #pragma unroll
    for (int i = 0; i < 7; ++i) { acc0[i] = f32x4{0,0,0,0}; acc1[i] = f32x4{0,0,0,0}; }
    #pragma unroll
    for (int i = 0; i < 7; ++i) if (i < NFW) {
        int ci = qh * 448 + cb + i * 16 + l15;
        gload_lds16(W2s + (size_t)ci * 8, slice + i * 512);
    }
    for (int kt = 0; kt < 13; ++kt) {
        asm volatile("s_waitcnt vmcnt(0)" ::: "memory");
        __builtin_amdgcn_sched_barrier(0);
        short8 bf[7];
        #pragma unroll
        for (int i = 0; i < 7; ++i) if (i < NFW)
            bf[i] = *(const short8*)(slice + i * 512 + lane * 8);
        int k0 = kt * 32 + qh * 8;
        short8 r0 = *(const short8*)&z1[(size_t)(rg * 32 + l15) * 416 + k0];
        short8 r1 = *(const short8*)&z1[(size_t)(rg * 32 + 16 + l15) * 416 + k0];
        float alv[8], btv[8];
        #pragma unroll
        for (int j = 0; j < 8; ++j) { alv[j] = al1[k0 + j]; btv[j] = bt1[k0 + j]; }
        asm volatile("s_waitcnt lgkmcnt(0)" ::: "memory");
        __builtin_amdgcn_sched_barrier(0);
        if (kt < 12) {
            #pragma unroll
            for (int i = 0; i < 7; ++i) if (i < NFW) {
                int ci = ((kt + 1) * 4 + qh) * 448 + cb + i * 16 + l15;
                gload_lds16(W2s + (size_t)ci * 8, slice + i * 512);
            }
        }
        short8 afA, afB;
        #pragma unroll
        for (int j = 0; j < 8; ++j) {
            float fa = fmaxf(0.f, alv[j] * bf2f((unsigned short)r0[j]) + btv[j]);
            float fb = fmaxf(0.f, alv[j] * bf2f((unsigned short)r1[j]) + btv[j]);
            afA[j] = (short)f2bf(fa); afB[j] = (short)f2bf(fb);
        }
        #pragma unroll
        for (int i = 0; i < 7; ++i) if (i < NFW) {
            acc0[i] = __builtin_amdgcn_mfma_f32_16x16x32_bf16(afA, bf[i], acc0[i], 0, 0, 0);
            acc1[i] = __builtin_amdgcn_mfma_f32_16x16x32_bf16(afB, bf[i], acc1[i], 0, 0, 0);
        }
    }
    __syncthreads();    // all waves done with al1/bt1/z1 reads before z2 write
    unsigned short* z2 = (unsigned short*)R2;    // [64][400], overlays al1/bt1
    #pragma unroll
    for (int i = 0; i < 7; ++i) if (i < NFW) {
        int col = cb + i * 16 + l15;
        float bv = b2[col];
        float ps = 0.f, pq = 0.f;
        #pragma unroll
        for (int q = 0; q < 4; ++q) {
            float v0 = acc0[i][q] + bv;
            float v1 = acc1[i][q] + bv;
            z2[(size_t)(rg * 32 + qh * 4 + q) * 400 + col] = f2bf(v0);
            z2[(size_t)(rg * 32 + 16 + qh * 4 + q) * 400 + col] = f2bf(v1);
            ps += v0 + v1; pq += v0 * v0 + v1 * v1;
        }
        ps += __shfl_xor(ps, 16, 64); ps += __shfl_xor(ps, 32, 64);
        pq += __shfl_xor(pq, 16, 64); pq += __shfl_xor(pq, 32, 64);
        if (qh == 0) { atomicAdd(&stc[832 + col], ps); atomicAdd(&stc[1248 + col], pq); }
    }
    grid.sync();    // S3: stats2 complete

    // ---- BN2 finalize into R1 (slices dead) + final dot ----
    float* al2 = (float*)smem;
    float* bt2 = (float*)(smem + 1600);
    for (int c = tid; c < 400; c += 512) {
        float gs = 0.f, gq = 0.f;
        #pragma unroll
        for (int cp = 0; cp < 4; ++cp) {
            gs += st[cp * 1664 + 832 + c];
            gq += st[cp * 1664 + 1248 + c];
        }
        float mean = gs * (1.f / 16384.f);
        float var  = gq * (1.f / 16384.f) - mean * mean;
        float a = g2[c] * rsqrtf(var + EPS);
        al2[c] = a;
        bt2[c] = be2[c] - mean * a;
    }
    __syncthreads();
    {
        int r = tid >> 3, oct = tid & 7;
        float facc = 0.f;
        for (int c = oct; c < 400; c += 8)
            facc += fmaxf(0.f, al2[c] * bf2f(z2[(size_t)r * 400 + c]) + bt2[c]) * W3[c];
        facc += __shfl_xor(facc, 1, 64);
        facc += __shfl_xor(facc, 2, 64);
        facc += __shfl_xor(facc, 4, 64);
        if (oct == 0) out[m0r + r] = base_s[r] + facc + b3[0];
    }
}

// =====================================================================
extern "C" void kernel_launch(void* const* d_in, const int* in_sizes, int n_in,
                              void* d_out, int out_size, void* d_ws, size_t ws_size,
                              hipStream_t stream)
{
    const int*   Xcat = (const int*)d_in[0];
    const float* Xd   = (const float*)d_in[1];
    const float* fm1  = (const float*)d_in[2];
    const float* emb  = (const float*)d_in[3];
    const float* Wd   = (const float*)d_in[4];
    const float* bd   = (const float*)d_in[5];
    const float* W1   = (const float*)d_in[6];
    const float* b1   = (const float*)d_in[7];
    const float* g1   = (const float*)d_in[8];
    const float* be1  = (const float*)d_in[9];
    const float* W2   = (const float*)d_in[10];
    const float* b2   = (const float*)d_in[11];
    const float* g2   = (const float*)d_in[12];
    const float* be2  = (const float*)d_in[13];
    const float* W3   = (const float*)d_in[14];
    const float* b3   = (const float*)d_in[15];

    char* ws = (char*)d_ws;
    unsigned short* W1s = (unsigned short*)(ws + W1S_OFF);
    unsigned short* W2s = (unsigned short*)(ws + W2S_OFF);
    float* st = (float*)(ws + ST_OFF);
    float* out = (float*)d_out;

    void* args[] = {
        (void*)&Xcat, (void*)&Xd, (void*)&fm1, (void*)&emb,
        (void*)&Wd, (void*)&bd, (void*)&W1, (void*)&b1, (void*)&g1, (void*)&be1,
        (void*)&W2, (void*)&b2, (void*)&g2, (void*)&be2, (void*)&W3, (void*)&b3,
        (void*)&W1s, (void*)&W2s, (void*)&st, (void*)&out
    };
    hipLaunchCooperativeKernel((const void*)deepfm_one, dim3(256), dim3(512),
                               args, 0, stream);
}

// Round 11
// 73.482 us; speedup vs baseline: 2.5282x; 2.5282x over previous
//
#include <hip/hip_runtime.h>
#include <stdint.h>

// ---------------- problem constants ----------------
#define B_ROWS 16384
#define NF 26
#define NV 100000
#define ND 13
#define NH 400
#define XPAD 448     // GEMM1 K padded (14 tiles of 32)
#define ZPAD 416     // GEMM2 K padded (13 tiles of 32)
#define EPS 1e-5f

typedef __attribute__((ext_vector_type(8))) short short8;
typedef __attribute__((ext_vector_type(4))) float f32x4;
typedef __attribute__((ext_vector_type(4))) unsigned int uint4v;

__device__ inline float bf2f(unsigned short u) {
    union { unsigned int i; float f; } v; v.i = (unsigned int)u << 16; return v.f;
}
__device__ inline unsigned short f2bf(float f) {
    union { float f; unsigned int i; } v; v.f = f;
    return (unsigned short)((v.i + 0x7fff + ((v.i >> 16) & 1)) >> 16);
}

// direct global->LDS DMA, 16B/lane; dest = wave-uniform base + lane*16
typedef __attribute__((address_space(1))) const unsigned int g_u32;
typedef __attribute__((address_space(3))) unsigned int l_u32;
__device__ __forceinline__ void gload_lds16(const void* g, void* l) {
    __builtin_amdgcn_global_load_lds((g_u32*)g, (l_u32*)l, 16, 0, 0);
}

// ---------------- ws layout (bytes) ----------------
// X  : bf16 [16384][448] (Z2 aliases X after GEMM1)
// Z1 : bf16 [16384][416]
// W1s/W2s staged; base f32[16384]; st = 4 replicas x 1664 f32
#define X_OFF    0
#define Z1_OFF   14680064
#define W1S_OFF  28311552
#define W2S_OFF  28712960
#define BASE_OFF 29085696
#define ST_OFF   29151232

// =====================================================================
// gather (blocks 0..1023) + W-staging/stat-zero (blocks 1024..1212)
// gather: 16 rows x 16 lanes; X bf16 + base. (R5-proven)
// =====================================================================
__global__ __launch_bounds__(256) void gather_prep(
    const int* __restrict__ Xcat, const float* __restrict__ Xdense,
    const float* __restrict__ fm1, const float* __restrict__ emb,
    const float* __restrict__ Wd, const float* __restrict__ bd,
    const float* __restrict__ W1, const float* __restrict__ W2,
    unsigned short* __restrict__ X, float* __restrict__ base,
    unsigned short* __restrict__ W1s, unsigned short* __restrict__ W2s,
    float* __restrict__ st)
{
    int tid = threadIdx.x;
    if (blockIdx.x >= 1024) {
        int c = (blockIdx.x - 1024) * 256 + tid;     // 0..48383
        if (c < 256) {
            for (int i = tid; i < 6656; i += 256) st[i] = 0.f;  // 4 replicas
        }
        const float* W; unsigned short* dst; int K; int cc;
        if (c < 25088) { W = W1; dst = W1s; K = 429; cc = c; }
        else           { W = W2; dst = W2s; K = 400; cc = c - 25088; }
        int n  = cc % 448;
        int q  = (cc / 448) & 3;
        int kt = cc / 1792;
        unsigned short o[8];
        #pragma unroll
        for (int j = 0; j < 8; ++j) {
            int k = kt * 32 + q * 8 + j;
            float v = (n < NH && k < K) ? W[(size_t)k * NH + n] : 0.f;
            o[j] = f2bf(v);
        }
        *(uint4v*)(dst + (size_t)cc * 8) = *(uint4v*)o;
        return;
    }
    int r = blockIdx.x * 16 + (tid >> 4);
    int k = tid & 15;
    const int* idxp = Xcat + (size_t)r * NF;
    unsigned short* xrow = X + (size_t)r * XPAD;

    float s = 0.f, ss = 0.f;
    #pragma unroll
    for (int f = 0; f < NF; ++f) {
        int idx = idxp[f];
        float v = emb[((size_t)f * NV + idx) * 16 + k];
        s += v; ss += v * v;
        xrow[f * 16 + k] = f2bf(v);
    }
    float fmsum = fm1[(size_t)k * NV + idxp[k]];
    if (k < NF - 16) fmsum += fm1[(size_t)(k + 16) * NV + idxp[k + 16]];
    float dsum = 0.f;
    if (k < ND) {
        float xd = Xdense[(size_t)r * ND + k];
        dsum = xd * Wd[k];
        xrow[NF * 16 + k] = f2bf(xd);
    }
    xrow[429 + k] = 0;
    if (k < 3) xrow[445 + k] = 0;

    float ix = s * s - ss;
    float rf = fmsum, rd = dsum;
    #pragma unroll
    for (int off = 8; off; off >>= 1) {
        ix += __shfl_xor(ix, off, 16);
        rf += __shfl_xor(rf, off, 16);
        rd += __shfl_xor(rd, off, 16);
    }
    if (k == 0) base[r] = 0.5f * ix + rf + rd + bd[0];
}

// =====================================================================
// gemm_v2: barrier-free per-wave-slice MFMA GEMM (K-loop = R10-proven).
// grid 256 x 512, 2 blocks/CU. Wave wv = (rg<<2)|w4:
//   rg = row half (rows bid*64 + rg*32 .. +31),
//   w4 = col quarter (cb..cb+16*NFW; NFW = 7,6,6,6).
// Each wave DMAs its own W slice (single-buffered, vmcnt-pipelined) and
// free-runs all NT tiles with NO __syncthreads in the loop.
// Stats: per-wave shuffle reduce -> 4-replica global atomics.
// =====================================================================
template<int NT, int LDA, bool APPLY_BN>
__global__ __launch_bounds__(512, 2) void gemm_v2(
    const unsigned short* __restrict__ A,
    const unsigned short* __restrict__ Wst,
    const float* __restrict__ bias,
    const float* __restrict__ st_all,   // replica base for BN input (K2)
    const float* __restrict__ g, const float* __restrict__ be,
    unsigned short* __restrict__ Z, int ldz, int padZ,
    float* __restrict__ st_out, int sumOff, int sqOff)
{
    __shared__ __align__(16) unsigned short slices[25600];  // 51,200 B
    __shared__ float alpha_s[416], beta_s[416];             // 3,328 B

    const int tid = threadIdx.x, bid = blockIdx.x;
    const int lane = tid & 63, wv = tid >> 6;
    const int rg = wv >> 2, w4 = wv & 3;
    const int l15 = lane & 15, qh = lane >> 4;
    const int cb = (w4 == 0) ? 0 : (112 + (w4 - 1) * 96);
    const int NFW = (w4 == 0) ? 7 : 6;
    unsigned short* slice =
        slices + rg * 12800 + ((w4 == 0) ? 0 : (3584 + (w4 - 1) * 3072));
    const int arowA = bid * 64 + rg * 32 + l15;
    const int arowB = arowA + 16;

    if constexpr (APPLY_BN) {
        for (int c = tid; c < ZPAD; c += 512) {
            float a = 0.f, b = 0.f;
            if (c < NH) {
                float gs = 0.f, gq = 0.f;
                #pragma unroll
                for (int cp = 0; cp < 4; ++cp) {
                    gs += st_all[cp * 1664 + c];
                    gq += st_all[cp * 1664 + 416 + c];
                }
                float mean = gs * (1.f / 16384.f);
                float var  = gq * (1.f / 16384.f) - mean * mean;
                a = g[c] * rsqrtf(var + EPS);
                b = be[c] - mean * a;
            }
            alpha_s[c] = a; beta_s[c] = b;
        }
        __syncthreads();
    }

    f32x4 acc0[7], acc1[7];
    #pragma unroll
    for (int i = 0; i < 7; ++i) { acc0[i] = f32x4{0,0,0,0}; acc1[i] = f32x4{0,0,0,0}; }

    auto stageW = [&](int kt) {
        #pragma unroll
        for (int i = 0; i < 7; ++i) if (i < NFW) {
            int ci = (kt * 4 + qh) * 448 + cb + i * 16 + l15;
            gload_lds16(Wst + (size_t)ci * 8, slice + i * 512);
        }
    };

    stageW(0);
    short8 afA_n = *(const short8*)(A + (size_t)arowA * LDA + qh * 8);
    short8 afB_n = *(const short8*)(A + (size_t)arowB * LDA + qh * 8);

    for (int kt = 0; kt < NT; ++kt) {
        asm volatile("s_waitcnt vmcnt(0)" ::: "memory");   // slice + af ready
        __builtin_amdgcn_sched_barrier(0);
        short8 bf[7];
        #pragma unroll
        for (int i = 0; i < 7; ++i) if (i < NFW)
            bf[i] = *(const short8*)(slice + i * 512 + lane * 8);
        short8 afA = afA_n, afB = afB_n;
        asm volatile("s_waitcnt lgkmcnt(0)" ::: "memory"); // ds_reads done
        __builtin_amdgcn_sched_barrier(0);
        if (kt + 1 < NT) {
            stageW(kt + 1);                                 // overwrite slice
            afA_n = *(const short8*)(A + (size_t)arowA * LDA + (kt + 1) * 32 + qh * 8);
            afB_n = *(const short8*)(A + (size_t)arowB * LDA + (kt + 1) * 32 + qh * 8);
        }
        if constexpr (APPLY_BN) {
            const int k0 = kt * 32 + qh * 8;
            #pragma unroll
            for (int j = 0; j < 8; ++j) {
                float fa = fmaxf(0.f, alpha_s[k0 + j] * bf2f((unsigned short)afA[j]) + beta_s[k0 + j]);
                float fb = fmaxf(0.f, alpha_s[k0 + j] * bf2f((unsigned short)afB[j]) + beta_s[k0 + j]);
                afA[j] = (short)f2bf(fa); afB[j] = (short)f2bf(fb);
            }
        }
        #pragma unroll
        for (int i = 0; i < 7; ++i) if (i < NFW) {
            acc0[i] = __builtin_amdgcn_mfma_f32_16x16x32_bf16(afA, bf[i], acc0[i], 0, 0, 0);
            acc1[i] = __builtin_amdgcn_mfma_f32_16x16x32_bf16(afB, bf[i], acc1[i], 0, 0, 0);
        }
    }

    // ---- epilogue: +bias, bf16 store, per-wave stats -> replica atomics ----
    float* stc = st_out + (bid & 3) * 1664;
    #pragma unroll
    for (int i = 0; i < 7; ++i) if (i < NFW) {
        int col = cb + i * 16 + l15;
        float bv = bias[col];
        float ps = 0.f, pq = 0.f;
        #pragma unroll
        for (int q = 0; q < 4; ++q) {
            float v0 = acc0[i][q] + bv;
            float v1 = acc1[i][q] + bv;
            Z[(size_t)(bid * 64 + rg * 32 + qh * 4 + q) * ldz + col] = f2bf(v0);
            Z[(size_t)(bid * 64 + rg * 32 + 16 + qh * 4 + q) * ldz + col] = f2bf(v1);
            ps += v0 + v1; pq += v0 * v0 + v1 * v1;
        }
        ps += __shfl_xor(ps, 16, 64); ps += __shfl_xor(ps, 32, 64);
        pq += __shfl_xor(pq, 16, 64); pq += __shfl_xor(pq, 32, 64);
        if (qh == 0) {
            atomicAdd(&stc[sumOff + col], ps);
            atomicAdd(&stc[sqOff + col], pq);
        }
    }
    if (padZ && w4 == 3) {   // zero cols 400..415 (this rg's 32 rows)
        #pragma unroll
        for (int rr = 0; rr < 8; ++rr)
            Z[(size_t)(bid * 64 + rg * 32 + rr * 4 + qh) * ldz + 400 + l15] = 0;
    }
}

// =====================================================================
// final: BN2 from replicas, then out[r] = base[r] + relu(.)·W3 + b3
// =====================================================================
__global__ __launch_bounds__(256) void final_kernel(
    const unsigned short* __restrict__ Z2,
    const float* __restrict__ st_all,
    const float* __restrict__ g2, const float* __restrict__ be2,
    const float* __restrict__ W3, const float* __restrict__ b3,
    const float* __restrict__ base, float* __restrict__ out)
{
    __shared__ float a2s[NH], b2s[NH], w3s[NH];
    int tid = threadIdx.x;
    for (int c = tid; c < NH; c += 256) {
        float gs = 0.f, gq = 0.f;
        #pragma unroll
        for (int cp = 0; cp < 4; ++cp) {
            gs += st_all[cp * 1664 + 832 + c];
            gq += st_all[cp * 1664 + 1248 + c];
        }
        float mean = gs * (1.f / 16384.f);
        float var  = gq * (1.f / 16384.f) - mean * mean;
        float a = g2[c] * rsqrtf(var + EPS);
        a2s[c] = a;
        b2s[c] = be2[c] - mean * a;
        w3s[c] = W3[c];
    }
    __syncthreads();
    int lane = tid & 63;
    int wv = tid >> 6;
    bool act = lane < 50;
    int cb = lane * 8;
    float al[8], bb[8], w3[8];
    #pragma unroll
    for (int j = 0; j < 8; ++j) {
        al[j] = act ? a2s[cb + j] : 0.f;
        bb[j] = act ? b2s[cb + j] : 0.f;
        w3[j] = act ? w3s[cb + j] : 0.f;
    }
    int r0 = blockIdx.x * 32 + wv * 8;
    float bias3 = b3[0];
    for (int t = 0; t < 8; t += 2) {
        int r = r0 + t;
        float acc0 = 0.f, acc1 = 0.f;
        if (act) {
            short8 z0 = *(const short8*)(Z2 + (size_t)r * ZPAD + cb);
            short8 z1 = *(const short8*)(Z2 + (size_t)(r + 1) * ZPAD + cb);
            #pragma unroll
            for (int j = 0; j < 8; ++j) {
                acc0 += fmaxf(0.f, al[j] * bf2f((unsigned short)z0[j]) + bb[j]) * w3[j];
                acc1 += fmaxf(0.f, al[j] * bf2f((unsigned short)z1[j]) + bb[j]) * w3[j];
            }
        }
        #pragma unroll
        for (int off = 32; off; off >>= 1) {
            acc0 += __shfl_xor(acc0, off, 64);
            acc1 += __shfl_xor(acc1, off, 64);
        }
        if (lane == 0) out[r] = base[r] + acc0 + bias3;
        if (lane == 1) out[r + 1] = base[r + 1] + acc1 + bias3;
    }
}

// =====================================================================
extern "C" void kernel_launch(void* const* d_in, const int* in_sizes, int n_in,
                              void* d_out, int out_size, void* d_ws, size_t ws_size,
                              hipStream_t stream)
{
    const int*   Xcat = (const int*)d_in[0];
    const float* Xd   = (const float*)d_in[1];
    const float* fm1  = (const float*)d_in[2];
    const float* emb  = (const float*)d_in[3];
    const float* Wd   = (const float*)d_in[4];
    const float* bd   = (const float*)d_in[5];
    const float* W1   = (const float*)d_in[6];
    const float* b1   = (const float*)d_in[7];
    const float* g1   = (const float*)d_in[8];
    const float* be1  = (const float*)d_in[9];
    const float* W2   = (const float*)d_in[10];
    const float* b2   = (const float*)d_in[11];
    const float* g2   = (const float*)d_in[12];
    const float* be2  = (const float*)d_in[13];
    const float* W3   = (const float*)d_in[14];
    const float* b3   = (const float*)d_in[15];

    char* ws = (char*)d_ws;
    unsigned short* X   = (unsigned short*)(ws + X_OFF);
    unsigned short* Z1  = (unsigned short*)(ws + Z1_OFF);
    unsigned short* Z2  = X;   // X dead after GEMM1
    unsigned short* W1s = (unsigned short*)(ws + W1S_OFF);
    unsigned short* W2s = (unsigned short*)(ws + W2S_OFF);
    float* base = (float*)(ws + BASE_OFF);
    float* st   = (float*)(ws + ST_OFF);
    float* out  = (float*)d_out;

    // 1: gather + W staging + 4-replica stat zero
    gather_prep<<<1213, 256, 0, stream>>>(Xcat, Xd, fm1, emb, Wd, bd, W1, W2,
                                          X, base, W1s, W2s, st);

    // 2: Z1 = X @ W1 + b1, stats1 (barrier-free per-wave GEMM)
    gemm_v2<14, XPAD, false><<<256, 512, 0, stream>>>(
        X, W1s, b1, nullptr, nullptr, nullptr, Z1, ZPAD, 1, st, 0, 416);

    // 3: Z2 = relu(bn1(Z1)) @ W2 + b2, stats2
    gemm_v2<13, ZPAD, true><<<256, 512, 0, stream>>>(
        Z1, W2s, b2, st, g1, be1, Z2, ZPAD, 0, st, 832, 1248);

    // 4: out = base + relu(bn2(Z2))·W3 + b3
    final_kernel<<<512, 256, 0, stream>>>(Z2, st, g2, be2, W3, b3, base, out);
}